// Round 3
// baseline (2084.901 us; speedup 1.0000x reference)
//
#include <hip/hip_runtime.h>

typedef unsigned short u16;
typedef __attribute__((ext_vector_type(4))) float f32x4;
typedef __attribute__((ext_vector_type(8))) short s16x8;
typedef __attribute__((ext_vector_type(8))) unsigned short u16x8;
typedef __attribute__((ext_vector_type(4))) unsigned short u16x4;

__device__ __forceinline__ float bf2f(u16 u) {
    union { unsigned int i; float f; } x; x.i = ((unsigned int)u) << 16; return x.f;
}
__device__ __forceinline__ u16 f2bf(float f) {
    union { float f; unsigned int i; } x; x.f = f;
    unsigned int r = x.i + 0x7FFFu + ((x.i >> 16) & 1u);
    return (u16)(r >> 16);
}

// ---------------- constants (problem is fixed-size) ----------------
#define BATCH 2
#define SEQ 2048
#define HID 2048
#define NH 32
#define NKV 8
#define HD 64
#define TOK (BATCH * SEQ)          // 4096
#define NQKV 3072                  // 2048 + 512 + 512

// ---------------- pre-pass kernels (device data is f32) ----------------
__global__ void k_f32_to_bf16(const float* __restrict__ src, u16* __restrict__ dst, int n4) {
    int i = blockIdx.x * blockDim.x + threadIdx.x;
    if (i >= n4) return;
    f32x4 v = ((const f32x4*)src)[i];
    u16x4 o;
    o[0] = f2bf(v[0]); o[1] = f2bf(v[1]); o[2] = f2bf(v[2]); o[3] = f2bf(v[3]);
    *(u16x4*)(dst + (size_t)i * 4) = o;
}

// src is K x N (row-major f32), dst is N x K bf16
__global__ void k_transpose_bf16(const float* __restrict__ src, u16* __restrict__ dst, int K, int N) {
    __shared__ float tile[32][33];
    int n0 = blockIdx.x * 32, k0 = blockIdx.y * 32;
    int tx = threadIdx.x, ty = threadIdx.y;   // (32, 8)
#pragma unroll
    for (int i = 0; i < 4; i++)
        tile[ty + i * 8][tx] = src[(size_t)(k0 + ty + i * 8) * N + n0 + tx];
    __syncthreads();
#pragma unroll
    for (int i = 0; i < 4; i++) {
        int n = n0 + ty + i * 8;
        dst[(size_t)n * K + k0 + tx] = f2bf(tile[tx][ty + i * 8]);
    }
}

__global__ void k_concat_bias(const float* __restrict__ bq, const float* __restrict__ bk,
                              const float* __restrict__ bv, float* __restrict__ out) {
    int i = blockIdx.x * blockDim.x + threadIdx.x;
    if (i >= NQKV) return;
    out[i] = (i < HID) ? bq[i] : (i < HID + 512 ? bk[i - HID] : bv[i - HID - 512]);
}

// ---------------- GEMM: C[M][N] = A[M][K](bf16) * BT[N][K](bf16)^T + bias(f32) ----------------
// bf16 MFMA 16x16x32, 128x128 tile, 4 waves (2x2), each wave 64x64.
template <int OUT_BF16>
__global__ __launch_bounds__(256) void k_gemm_bt(const u16* __restrict__ A, const u16* __restrict__ BT,
                                                 const float* __restrict__ bias, void* __restrict__ Cout,
                                                 int M, int N, int K, int lda, int ldb) {
    __shared__ u16 As[128][40];   // pad 8 bf16 -> row stride 80B
    __shared__ u16 Bs[128][40];
    const int t = threadIdx.x;
    const int brow = blockIdx.y * 128, bcol = blockIdx.x * 128;
    const int wid = t >> 6, lane = t & 63;
    const int wr = (wid >> 1) * 64, wc = (wid & 1) * 64;
    const int lr = lane & 15;               // A row / B col / D col
    const int lk = (lane >> 4) * 8;         // K offset of 8-elem fragment
    f32x4 acc[4][4] = {};

    for (int k0 = 0; k0 < K; k0 += 32) {
        __syncthreads();
#pragma unroll
        for (int c = t; c < 512; c += 256) {
            int row = c >> 2, col8 = (c & 3) << 3;
            *(u16x8*)(&As[row][col8]) = *(const u16x8*)(A + (size_t)(brow + row) * lda + k0 + col8);
            *(u16x8*)(&Bs[row][col8]) = *(const u16x8*)(BT + (size_t)(bcol + row) * ldb + k0 + col8);
        }
        __syncthreads();
        s16x8 af[4], bf[4];
#pragma unroll
        for (int mi = 0; mi < 4; mi++) af[mi] = *(const s16x8*)(&As[wr + mi * 16 + lr][lk]);
#pragma unroll
        for (int ni = 0; ni < 4; ni++) bf[ni] = *(const s16x8*)(&Bs[wc + ni * 16 + lr][lk]);
#pragma unroll
        for (int mi = 0; mi < 4; mi++)
#pragma unroll
            for (int ni = 0; ni < 4; ni++)
                acc[mi][ni] = __builtin_amdgcn_mfma_f32_16x16x32_bf16(af[mi], bf[ni], acc[mi][ni], 0, 0, 0);
    }

    const int drow = (lane >> 4) << 2;
#pragma unroll
    for (int mi = 0; mi < 4; mi++) {
#pragma unroll
        for (int ni = 0; ni < 4; ni++) {
#pragma unroll
            for (int r = 0; r < 4; r++) {
                int row = brow + wr + mi * 16 + drow + r;
                int col = bcol + wc + ni * 16 + lr;
                float v = acc[mi][ni][r] + bias[col];
                if (OUT_BF16) ((u16*)Cout)[(size_t)row * N + col] = f2bf(v);
                else          ((float*)Cout)[(size_t)row * N + col] = v;
            }
        }
    }
}

// ---------------- RMSNorm + RoPE epilogue ----------------
// grid (TOK, 48): slots 0..31 q heads, 32..39 k heads, 40..47 v heads. 64 threads.
__global__ __launch_bounds__(64) void k_norm_rope(const float* __restrict__ QKV,
                                                  const float* __restrict__ qn_w, const float* __restrict__ kn_w,
                                                  const float* __restrict__ cosT, const float* __restrict__ sinT,
                                                  u16* __restrict__ Qp, u16* __restrict__ Kp, u16* __restrict__ Vp) {
    int token = blockIdx.x;
    int slot = blockIdx.y;
    int d = threadIdx.x;
    int b = token >> 11, s = token & 2047;
    const float* row = QKV + (size_t)token * NQKV;
    if (slot < 40) {
        bool isq = slot < 32;
        int h = isq ? slot : slot - 32;
        float x = isq ? row[h * HD + d] : row[HID + h * HD + d];
        float ss = x * x;
#pragma unroll
        for (int o = 32; o; o >>= 1) ss += __shfl_xor(ss, o);
        float r = rsqrtf(ss * (1.0f / 64.0f) + 1e-6f);
        float xn = x * r * (isq ? qn_w[d] : kn_w[d]);
        float part = __shfl_xor(xn, 32);
        float sign = (d < 32) ? -1.f : 1.f;
        float o = xn * cosT[s * HD + d] + sign * part * sinT[s * HD + d];
        if (isq) Qp[(((size_t)(b * NH + h) * SEQ + s) * HD) + d] = f2bf(o);
        else     Kp[(((size_t)(b * NKV + h) * SEQ + s) * HD) + d] = f2bf(o);
    } else {
        int h = slot - 40;
        Vp[(((size_t)(b * NKV + h) * SEQ + s) * HD) + d] = f2bf(row[HID + 512 + h * HD + d]);
    }
}

// ---------------- flash attention (vector f32) ----------------
// 1 wave per block; thread t owns q-row qt*64+t; K/V tiles of 64 staged in LDS.
__global__ __launch_bounds__(64) void k_attn(const u16* __restrict__ Qp, const u16* __restrict__ Kp,
                                             const u16* __restrict__ Vp, u16* __restrict__ AO) {
    __shared__ float Ks[64][68];
    __shared__ float Vs[64][68];
    int bid = blockIdx.x;
    int qt = bid & 31, h = (bid >> 5) & 31, b = bid >> 10;
    int t = threadIdx.x;
    int kvh = h >> 2;
    int sq = qt * 64 + t;

    const u16* qrow = Qp + ((size_t)(b * NH + h) * SEQ + sq) * HD;
    f32x4 q4[16];
#pragma unroll
    for (int j = 0; j < 8; j++) {
        u16x8 v = *(const u16x8*)(qrow + j * 8);
        f32x4 lo, hi;
        lo[0] = bf2f(v[0]); lo[1] = bf2f(v[1]); lo[2] = bf2f(v[2]); lo[3] = bf2f(v[3]);
        hi[0] = bf2f(v[4]); hi[1] = bf2f(v[5]); hi[2] = bf2f(v[6]); hi[3] = bf2f(v[7]);
        q4[j * 2] = lo * 0.125f; q4[j * 2 + 1] = hi * 0.125f;
    }
    float m = -1e30f, l = 0.f;
    f32x4 O[16];
#pragma unroll
    for (int c = 0; c < 16; c++) O[c] = (f32x4){0.f, 0.f, 0.f, 0.f};

    const u16* Kb = Kp + (size_t)(b * NKV + kvh) * SEQ * HD;
    const u16* Vb = Vp + (size_t)(b * NKV + kvh) * SEQ * HD;

    for (int kt = 0; kt <= qt; kt++) {
        int k0 = kt * 64;
        __syncthreads();
#pragma unroll
        for (int j2 = 0; j2 < 8; j2++) {
            u16x8 kv = *(const u16x8*)(Kb + (size_t)(k0 + t) * HD + j2 * 8);
            u16x8 vv = *(const u16x8*)(Vb + (size_t)(k0 + t) * HD + j2 * 8);
#pragma unroll
            for (int e = 0; e < 8; e++) {
                Ks[t][j2 * 8 + e] = bf2f(kv[e]);
                Vs[t][j2 * 8 + e] = bf2f(vv[e]);
            }
        }
        __syncthreads();
        int jmax = (kt == qt) ? (t + 1) : 64;
        for (int j = 0; j < jmax; j++) {
            const f32x4* kr = (const f32x4*)(&Ks[j][0]);
            f32x4 s4 = {0.f, 0.f, 0.f, 0.f};
#pragma unroll
            for (int c = 0; c < 16; c++) s4 += q4[c] * kr[c];
            float sc = s4[0] + s4[1] + s4[2] + s4[3];
            if (sc > m) {
                float f = __expf(m - sc);
                m = sc;
                l *= f;
#pragma unroll
                for (int c = 0; c < 16; c++) O[c] *= f;
            }
            float p = __expf(sc - m);
            l += p;
            const f32x4* vr = (const f32x4*)(&Vs[j][0]);
#pragma unroll
            for (int c = 0; c < 16; c++) O[c] += p * vr[c];
        }
    }
    float inv = 1.0f / l;
    u16* orow = AO + ((size_t)(b * SEQ) + sq) * (NH * HD) + h * HD;
#pragma unroll
    for (int c = 0; c < 16; c++) {
        f32x4 o = O[c] * inv;
        u16x4 w;
        w[0] = f2bf(o[0]); w[1] = f2bf(o[1]); w[2] = f2bf(o[2]); w[3] = f2bf(o[3]);
        *(u16x4*)(orow + c * 4) = w;
    }
}

// ---------------- launch ----------------
extern "C" void kernel_launch(void* const* d_in, const int* in_sizes, int n_in,
                              void* d_out, int out_size, void* d_ws, size_t ws_size,
                              hipStream_t stream) {
    const float* hs   = (const float*)d_in[0];
    const float* Wq   = (const float*)d_in[1];
    const float* bq   = (const float*)d_in[2];
    const float* Wk   = (const float*)d_in[3];
    const float* bk   = (const float*)d_in[4];
    const float* Wv   = (const float*)d_in[5];
    const float* bv   = (const float*)d_in[6];
    const float* Wo   = (const float*)d_in[7];
    const float* bo   = (const float*)d_in[8];
    const float* qn_w = (const float*)d_in[9];
    const float* kn_w = (const float*)d_in[10];
    const float* cosT = (const float*)d_in[11];
    const float* sinT = (const float*)d_in[12];

    // workspace layout (bytes, 256-aligned)
    char* ws = (char*)d_ws;
    size_t off = 0;
    auto alloc = [&](size_t bytes) { char* p = ws + off; off = (off + bytes + 255) & ~(size_t)255; return p; };
    u16*   Xb    = (u16*)  alloc((size_t)TOK * HID * 2);        // 16.8 MB
    u16*   WTqkv = (u16*)  alloc((size_t)NQKV * HID * 2);       // 12.6 MB
    u16*   WoT   = (u16*)  alloc((size_t)HID * HID * 2);        // 8.4 MB
    float* bqkv  = (float*)alloc((size_t)NQKV * 4);
    float* QKV   = (float*)alloc((size_t)TOK * NQKV * 4);       // 50.3 MB
    u16*   Qp    = (u16*)  alloc((size_t)BATCH * NH * SEQ * HD * 2);   // 16.8 MB
    u16*   Kp    = (u16*)  alloc((size_t)BATCH * NKV * SEQ * HD * 2);  // 4.2 MB
    u16*   Vp    = (u16*)  alloc((size_t)BATCH * NKV * SEQ * HD * 2);  // 4.2 MB
    u16*   AO    = (u16*)  alloc((size_t)TOK * HID * 2);        // 16.8 MB
    (void)ws_size;

    // 1. convert X to bf16
    k_f32_to_bf16<<<(TOK * HID / 4 + 255) / 256, 256, 0, stream>>>(hs, Xb, TOK * HID / 4);
    // 2. transpose weights to N x K bf16
    dim3 tb(32, 8);
    k_transpose_bf16<<<dim3(HID / 32, HID / 32), tb, 0, stream>>>(Wq, WTqkv, HID, HID);
    k_transpose_bf16<<<dim3(512 / 32, HID / 32), tb, 0, stream>>>(Wk, WTqkv + (size_t)HID * HID, HID, 512);
    k_transpose_bf16<<<dim3(512 / 32, HID / 32), tb, 0, stream>>>(Wv, WTqkv + (size_t)(HID + 512) * HID, HID, 512);
    k_transpose_bf16<<<dim3(HID / 32, HID / 32), tb, 0, stream>>>(Wo, WoT, HID, HID);
    k_concat_bias<<<(NQKV + 255) / 256, 256, 0, stream>>>(bq, bk, bv, bqkv);
    // 3. QKV GEMM: [4096 x 3072] -> f32
    k_gemm_bt<0><<<dim3(NQKV / 128, TOK / 128), 256, 0, stream>>>(Xb, WTqkv, bqkv, QKV, TOK, NQKV, HID, HID, HID);
    // 4. RMSNorm + RoPE, scatter to [B][H][S][64] bf16
    k_norm_rope<<<dim3(TOK, 48), 64, 0, stream>>>(QKV, qn_w, kn_w, cosT, sinT, Qp, Kp, Vp);
    // 5. causal GQA attention
    k_attn<<<BATCH * NH * (SEQ / 64), 64, 0, stream>>>(Qp, Kp, Vp, AO);
    // 6. output projection -> f32 d_out
    k_gemm_bt<0><<<dim3(HID / 128, TOK / 128), 256, 0, stream>>>(AO, WoT, bo, d_out, TOK, HID, HID, HID, HID);
}

// Round 4
// 339.870 us; speedup vs baseline: 6.1344x; 6.1344x over previous
//
#include <hip/hip_runtime.h>

typedef unsigned short u16;
typedef __attribute__((ext_vector_type(4))) float f32x4;
typedef __attribute__((ext_vector_type(8))) short s16x8;
typedef __attribute__((ext_vector_type(8))) unsigned short u16x8;
typedef __attribute__((ext_vector_type(4))) unsigned short u16x4;

__device__ __forceinline__ float bf2f(u16 u) {
    union { unsigned int i; float f; } x; x.i = ((unsigned int)u) << 16; return x.f;
}
__device__ __forceinline__ u16 f2bf(float f) {
    union { float f; unsigned int i; } x; x.f = f;
    unsigned int r = x.i + 0x7FFFu + ((x.i >> 16) & 1u);
    return (u16)(r >> 16);
}

// ---------------- constants (problem is fixed-size) ----------------
#define BATCH 2
#define SEQ 2048
#define HID 2048
#define NH 32
#define NKV 8
#define HD 64
#define TOK (BATCH * SEQ)          // 4096
#define NQKV 3072                  // 2048 + 512 + 512

// ---------------- pre-pass kernels (device data is f32) ----------------
__global__ void k_f32_to_bf16(const float* __restrict__ src, u16* __restrict__ dst, int n4) {
    int i = blockIdx.x * blockDim.x + threadIdx.x;
    if (i >= n4) return;
    f32x4 v = ((const f32x4*)src)[i];
    u16x4 o;
    o[0] = f2bf(v[0]); o[1] = f2bf(v[1]); o[2] = f2bf(v[2]); o[3] = f2bf(v[3]);
    *(u16x4*)(dst + (size_t)i * 4) = o;
}

// src is K x N (row-major f32), dst is N x K bf16
__global__ void k_transpose_bf16(const float* __restrict__ src, u16* __restrict__ dst, int K, int N) {
    __shared__ float tile[32][33];
    int n0 = blockIdx.x * 32, k0 = blockIdx.y * 32;
    int tx = threadIdx.x, ty = threadIdx.y;   // (32, 8)
#pragma unroll
    for (int i = 0; i < 4; i++)
        tile[ty + i * 8][tx] = src[(size_t)(k0 + ty + i * 8) * N + n0 + tx];
    __syncthreads();
#pragma unroll
    for (int i = 0; i < 4; i++) {
        int n = n0 + ty + i * 8;
        dst[(size_t)n * K + k0 + tx] = f2bf(tile[tx][ty + i * 8]);
    }
}

// per-head transpose: src [SEQ][HD] bf16 -> dst [HD][SEQ] bf16
__global__ void k_transpose_v(const u16* __restrict__ src, u16* __restrict__ dst) {
    __shared__ u16 tile[32][34];
    const u16* s = src + (size_t)blockIdx.z * SEQ * HD;
    u16* d = dst + (size_t)blockIdx.z * SEQ * HD;
    int d0 = blockIdx.x * 32;
    int s0 = blockIdx.y * 32;
    int tx = threadIdx.x, ty = threadIdx.y;   // (32, 8)
#pragma unroll
    for (int i = 0; i < 4; i++)
        tile[ty + i * 8][tx] = s[(size_t)(s0 + ty + i * 8) * HD + d0 + tx];
    __syncthreads();
#pragma unroll
    for (int i = 0; i < 4; i++)
        d[(size_t)(d0 + ty + i * 8) * SEQ + s0 + tx] = tile[tx][ty + i * 8];
}

__global__ void k_concat_bias(const float* __restrict__ bq, const float* __restrict__ bk,
                              const float* __restrict__ bv, float* __restrict__ out) {
    int i = blockIdx.x * blockDim.x + threadIdx.x;
    if (i >= NQKV) return;
    out[i] = (i < HID) ? bq[i] : (i < HID + 512 ? bk[i - HID] : bv[i - HID - 512]);
}

// ---------------- GEMM: C[M][N] = A[M][K](bf16) * BT[N][K](bf16)^T + bias(f32) ----------------
template <int OUT_BF16>
__global__ __launch_bounds__(256) void k_gemm_bt(const u16* __restrict__ A, const u16* __restrict__ BT,
                                                 const float* __restrict__ bias, void* __restrict__ Cout,
                                                 int M, int N, int K, int lda, int ldb) {
    __shared__ u16 As[128][40];
    __shared__ u16 Bs[128][40];
    const int t = threadIdx.x;
    const int brow = blockIdx.y * 128, bcol = blockIdx.x * 128;
    const int wid = t >> 6, lane = t & 63;
    const int wr = (wid >> 1) * 64, wc = (wid & 1) * 64;
    const int lr = lane & 15;
    const int lk = (lane >> 4) * 8;
    f32x4 acc[4][4] = {};

    for (int k0 = 0; k0 < K; k0 += 32) {
        __syncthreads();
#pragma unroll
        for (int c = t; c < 512; c += 256) {
            int row = c >> 2, col8 = (c & 3) << 3;
            *(u16x8*)(&As[row][col8]) = *(const u16x8*)(A + (size_t)(brow + row) * lda + k0 + col8);
            *(u16x8*)(&Bs[row][col8]) = *(const u16x8*)(BT + (size_t)(bcol + row) * ldb + k0 + col8);
        }
        __syncthreads();
        s16x8 af[4], bf[4];
#pragma unroll
        for (int mi = 0; mi < 4; mi++) af[mi] = *(const s16x8*)(&As[wr + mi * 16 + lr][lk]);
#pragma unroll
        for (int ni = 0; ni < 4; ni++) bf[ni] = *(const s16x8*)(&Bs[wc + ni * 16 + lr][lk]);
#pragma unroll
        for (int mi = 0; mi < 4; mi++)
#pragma unroll
            for (int ni = 0; ni < 4; ni++)
                acc[mi][ni] = __builtin_amdgcn_mfma_f32_16x16x32_bf16(af[mi], bf[ni], acc[mi][ni], 0, 0, 0);
    }

    const int drow = (lane >> 4) << 2;
#pragma unroll
    for (int mi = 0; mi < 4; mi++) {
#pragma unroll
        for (int ni = 0; ni < 4; ni++) {
#pragma unroll
            for (int r = 0; r < 4; r++) {
                int row = brow + wr + mi * 16 + drow + r;
                int col = bcol + wc + ni * 16 + lr;
                float v = acc[mi][ni][r] + bias[col];
                if (OUT_BF16) ((u16*)Cout)[(size_t)row * N + col] = f2bf(v);
                else          ((float*)Cout)[(size_t)row * N + col] = v;
            }
        }
    }
}

// ---------------- RMSNorm + RoPE epilogue ----------------
__global__ __launch_bounds__(64) void k_norm_rope(const float* __restrict__ QKV,
                                                  const float* __restrict__ qn_w, const float* __restrict__ kn_w,
                                                  const float* __restrict__ cosT, const float* __restrict__ sinT,
                                                  u16* __restrict__ Qp, u16* __restrict__ Kp, u16* __restrict__ Vp) {
    int token = blockIdx.x;
    int slot = blockIdx.y;
    int d = threadIdx.x;
    int b = token >> 11, s = token & 2047;
    const float* row = QKV + (size_t)token * NQKV;
    if (slot < 40) {
        bool isq = slot < 32;
        int h = isq ? slot : slot - 32;
        float x = isq ? row[h * HD + d] : row[HID + h * HD + d];
        float ss = x * x;
#pragma unroll
        for (int o = 32; o; o >>= 1) ss += __shfl_xor(ss, o);
        float r = rsqrtf(ss * (1.0f / 64.0f) + 1e-6f);
        float xn = x * r * (isq ? qn_w[d] : kn_w[d]);
        float part = __shfl_xor(xn, 32);
        float sign = (d < 32) ? -1.f : 1.f;
        float o = xn * cosT[s * HD + d] + sign * part * sinT[s * HD + d];
        if (isq) Qp[(((size_t)(b * NH + h) * SEQ + s) * HD) + d] = f2bf(o);
        else     Kp[(((size_t)(b * NKV + h) * SEQ + s) * HD) + d] = f2bf(o);
    } else {
        int h = slot - 40;
        Vp[(((size_t)(b * NKV + h) * SEQ + s) * HD) + d] = f2bf(row[HID + 512 + h * HD + d]);
    }
}

// ---------------- MFMA flash attention ----------------
// block = 4 waves, 128 q-rows (32/wave). K-tile 64 in LDS; V^T tile in LDS;
// P re-shaped via per-wave LDS. Online softmax per q-row (16-lane shfl groups).
__global__ __launch_bounds__(256) void k_attn_mfma(const u16* __restrict__ Qp, const u16* __restrict__ Kp,
                                                   const u16* __restrict__ VpT, u16* __restrict__ AO) {
    __shared__ u16 K_lds[64][72];
    __shared__ u16 VT_lds[64][72];
    __shared__ u16 P_lds[4][32][76];
    const int bid = blockIdx.x;
    const int qt = 15 - (bid >> 6);        // heavy tiles dispatched first
    const int hh = bid & 63;
    const int b = hh >> 5, h = hh & 31, kvh = h >> 2;
    const int t = threadIdx.x, w = t >> 6, lane = t & 63;
    const int lr = lane & 15, g = lane >> 4;
    const int qb = qt * 128 + w * 32;

    const u16* Qb = Qp + (size_t)(b * NH + h) * SEQ * HD;
    const u16* Kb = Kp + (size_t)(b * NKV + kvh) * SEQ * HD;
    const u16* Vb = VpT + (size_t)(b * NKV + kvh) * HD * SEQ;

    // hoist Q fragments (A-operand: row = lr, k = 32*ks + 8*g + j)
    s16x8 aq[2][2];
#pragma unroll
    for (int mi = 0; mi < 2; mi++)
#pragma unroll
        for (int ks = 0; ks < 2; ks++)
            aq[mi][ks] = *(const s16x8*)(Qb + (size_t)(qb + mi * 16 + lr) * HD + ks * 32 + g * 8);

    f32x4 O[2][4];
    float m[2][4], l[2][4];
#pragma unroll
    for (int mi = 0; mi < 2; mi++)
#pragma unroll
        for (int x = 0; x < 4; x++) { O[mi][x] = (f32x4){0.f, 0.f, 0.f, 0.f}; m[mi][x] = -1e30f; l[mi][x] = 0.f; }

    const int nkt = 2 * (qt + 1);
    for (int kt = 0; kt < nkt; kt++) {
        const int k0 = kt * 64;
        __syncthreads();
#pragma unroll
        for (int i = 0; i < 2; i++) {
            int c = t + 256 * i, row = c >> 3, col8 = (c & 7) * 8;
            *(u16x8*)&K_lds[row][col8]  = *(const u16x8*)(Kb + (size_t)(k0 + row) * HD + col8);
            *(u16x8*)&VT_lds[row][col8] = *(const u16x8*)(Vb + (size_t)row * SEQ + k0 + col8);
        }
        __syncthreads();
        if (k0 > qb + 31) continue;     // wave-uniform skip; no barrier inside

        // ---- S = Q K^T ----
        f32x4 s[2][4];
#pragma unroll
        for (int mi = 0; mi < 2; mi++)
#pragma unroll
            for (int ni = 0; ni < 4; ni++) s[mi][ni] = (f32x4){0.f, 0.f, 0.f, 0.f};
#pragma unroll
        for (int ni = 0; ni < 4; ni++) {
            s16x8 bk0 = *(const s16x8*)&K_lds[ni * 16 + lr][g * 8];
            s16x8 bk1 = *(const s16x8*)&K_lds[ni * 16 + lr][32 + g * 8];
#pragma unroll
            for (int mi = 0; mi < 2; mi++) {
                s[mi][ni] = __builtin_amdgcn_mfma_f32_16x16x32_bf16(aq[mi][0], bk0, s[mi][ni], 0, 0, 0);
                s[mi][ni] = __builtin_amdgcn_mfma_f32_16x16x32_bf16(aq[mi][1], bk1, s[mi][ni], 0, 0, 0);
            }
        }

        const bool diag = (k0 + 63 > qb);
#pragma unroll
        for (int mi = 0; mi < 2; mi++)
#pragma unroll
            for (int ni = 0; ni < 4; ni++)
#pragma unroll
                for (int r = 0; r < 4; r++) {
                    float v = s[mi][ni][r] * 0.125f;
                    if (diag && (k0 + ni * 16 + lr > qb + mi * 16 + 4 * g + r)) v = -1e30f;
                    s[mi][ni][r] = v;
                }

        // ---- online softmax (per q-row; row spans the 16-lane col group) ----
#pragma unroll
        for (int mi = 0; mi < 2; mi++) {
#pragma unroll
            for (int r = 0; r < 4; r++) {
                float pm = fmaxf(fmaxf(s[mi][0][r], s[mi][1][r]), fmaxf(s[mi][2][r], s[mi][3][r]));
#pragma unroll
                for (int off = 1; off < 16; off <<= 1) pm = fmaxf(pm, __shfl_xor(pm, off));
                float mn = fmaxf(m[mi][r], pm);
                float f = __expf(m[mi][r] - mn);
                m[mi][r] = mn;
                float ps = 0.f;
#pragma unroll
                for (int ni = 0; ni < 4; ni++) {
                    float p = __expf(s[mi][ni][r] - mn);
                    s[mi][ni][r] = p;
                    ps += p;
                }
#pragma unroll
                for (int off = 1; off < 16; off <<= 1) ps += __shfl_xor(ps, off);
                l[mi][r] = l[mi][r] * f + ps;
#pragma unroll
                for (int nd = 0; nd < 4; nd++) O[mi][nd][r] *= f;
            }
        }

        // ---- P (C-layout) -> LDS -> A-layout ----
#pragma unroll
        for (int mi = 0; mi < 2; mi++)
#pragma unroll
            for (int ni = 0; ni < 4; ni++)
#pragma unroll
                for (int r = 0; r < 4; r++)
                    P_lds[w][mi * 16 + 4 * g + r][ni * 16 + lr] = f2bf(s[mi][ni][r]);

        // ---- O += P V ----
#pragma unroll
        for (int ks = 0; ks < 2; ks++) {
            s16x8 pa0 = *(const s16x8*)&P_lds[w][lr][ks * 32 + g * 8];
            s16x8 pa1 = *(const s16x8*)&P_lds[w][16 + lr][ks * 32 + g * 8];
#pragma unroll
            for (int nd = 0; nd < 4; nd++) {
                s16x8 vb = *(const s16x8*)&VT_lds[nd * 16 + lr][ks * 32 + g * 8];
                O[0][nd] = __builtin_amdgcn_mfma_f32_16x16x32_bf16(pa0, vb, O[0][nd], 0, 0, 0);
                O[1][nd] = __builtin_amdgcn_mfma_f32_16x16x32_bf16(pa1, vb, O[1][nd], 0, 0, 0);
            }
        }
    }

    // ---- epilogue: O/l -> AO[tok][h*64+d] bf16 ----
#pragma unroll
    for (int mi = 0; mi < 2; mi++) {
#pragma unroll
        for (int r = 0; r < 4; r++) {
            float inv = 1.0f / l[mi][r];
            int q = qb + mi * 16 + 4 * g + r;
            u16* orow = AO + (size_t)(b * SEQ + q) * (NH * HD) + h * HD;
#pragma unroll
            for (int nd = 0; nd < 4; nd++)
                orow[nd * 16 + lr] = f2bf(O[mi][nd][r] * inv);
        }
    }
}

// ---------------- launch ----------------
extern "C" void kernel_launch(void* const* d_in, const int* in_sizes, int n_in,
                              void* d_out, int out_size, void* d_ws, size_t ws_size,
                              hipStream_t stream) {
    const float* hs   = (const float*)d_in[0];
    const float* Wq   = (const float*)d_in[1];
    const float* bq   = (const float*)d_in[2];
    const float* Wk   = (const float*)d_in[3];
    const float* bk   = (const float*)d_in[4];
    const float* Wv   = (const float*)d_in[5];
    const float* bv   = (const float*)d_in[6];
    const float* Wo   = (const float*)d_in[7];
    const float* bo   = (const float*)d_in[8];
    const float* qn_w = (const float*)d_in[9];
    const float* kn_w = (const float*)d_in[10];
    const float* cosT = (const float*)d_in[11];
    const float* sinT = (const float*)d_in[12];

    char* ws = (char*)d_ws;
    size_t off = 0;
    auto alloc = [&](size_t bytes) { char* p = ws + off; off = (off + bytes + 255) & ~(size_t)255; return p; };
    u16*   Xb    = (u16*)  alloc((size_t)TOK * HID * 2);
    u16*   WTqkv = (u16*)  alloc((size_t)NQKV * HID * 2);
    u16*   WoT   = (u16*)  alloc((size_t)HID * HID * 2);
    float* bqkv  = (float*)alloc((size_t)NQKV * 4);
    float* QKV   = (float*)alloc((size_t)TOK * NQKV * 4);
    u16*   Qp    = (u16*)  alloc((size_t)BATCH * NH * SEQ * HD * 2);
    u16*   Kp    = (u16*)  alloc((size_t)BATCH * NKV * SEQ * HD * 2);
    u16*   Vp    = (u16*)  alloc((size_t)BATCH * NKV * SEQ * HD * 2);
    u16*   VpT   = (u16*)  alloc((size_t)BATCH * NKV * SEQ * HD * 2);
    u16*   AO    = (u16*)  alloc((size_t)TOK * HID * 2);
    (void)ws_size;

    k_f32_to_bf16<<<(TOK * HID / 4 + 255) / 256, 256, 0, stream>>>(hs, Xb, TOK * HID / 4);
    dim3 tb(32, 8);
    k_transpose_bf16<<<dim3(HID / 32, HID / 32), tb, 0, stream>>>(Wq, WTqkv, HID, HID);
    k_transpose_bf16<<<dim3(512 / 32, HID / 32), tb, 0, stream>>>(Wk, WTqkv + (size_t)HID * HID, HID, 512);
    k_transpose_bf16<<<dim3(512 / 32, HID / 32), tb, 0, stream>>>(Wv, WTqkv + (size_t)(HID + 512) * HID, HID, 512);
    k_transpose_bf16<<<dim3(HID / 32, HID / 32), tb, 0, stream>>>(Wo, WoT, HID, HID);
    k_concat_bias<<<(NQKV + 255) / 256, 256, 0, stream>>>(bq, bk, bv, bqkv);
    // QKV GEMM -> f32
    k_gemm_bt<0><<<dim3(NQKV / 128, TOK / 128), 256, 0, stream>>>(Xb, WTqkv, bqkv, QKV, TOK, NQKV, HID, HID, HID);
    // norm + rope
    k_norm_rope<<<dim3(TOK, 48), 64, 0, stream>>>(QKV, qn_w, kn_w, cosT, sinT, Qp, Kp, Vp);
    // V transpose per head: [SEQ][HD] -> [HD][SEQ]
    k_transpose_v<<<dim3(HD / 32, SEQ / 32, BATCH * NKV), tb, 0, stream>>>(Vp, VpT);
    // MFMA flash attention
    k_attn_mfma<<<BATCH * NH * (SEQ / 128), 256, 0, stream>>>(Qp, Kp, VpT, AO);
    // output projection -> f32 d_out
    k_gemm_bt<0><<<dim3(HID / 128, TOK / 128), 256, 0, stream>>>(AO, WoT, bo, d_out, TOK, HID, HID, HID, HID);
}

// Round 5
// 316.300 us; speedup vs baseline: 6.5915x; 1.0745x over previous
//
#include <hip/hip_runtime.h>

typedef unsigned short u16;
typedef __attribute__((ext_vector_type(4))) float f32x4;
typedef __attribute__((ext_vector_type(8))) short s16x8;
typedef __attribute__((ext_vector_type(8))) unsigned short u16x8;
typedef __attribute__((ext_vector_type(4))) unsigned short u16x4;

__device__ __forceinline__ float bf2f(u16 u) {
    union { unsigned int i; float f; } x; x.i = ((unsigned int)u) << 16; return x.f;
}
__device__ __forceinline__ u16 f2bf(float f) {
    union { float f; unsigned int i; } x; x.f = f;
    unsigned int r = x.i + 0x7FFFu + ((x.i >> 16) & 1u);
    return (u16)(r >> 16);
}
__device__ __forceinline__ void gload16(const void* g, void* l) {
    __builtin_amdgcn_global_load_lds((const __attribute__((address_space(1))) void*)g,
                                     (__attribute__((address_space(3))) void*)l, 16, 0, 0);
}

// ---------------- constants (problem is fixed-size) ----------------
#define BATCH 2
#define SEQ 2048
#define HID 2048
#define NH 32
#define NKV 8
#define HD 64
#define TOK (BATCH * SEQ)          // 4096
#define NQKV 3072                  // 2048 + 512 + 512

// ---------------- pre-pass kernels (device data is f32) ----------------
__global__ void k_f32_to_bf16(const float* __restrict__ src, u16* __restrict__ dst, int n4) {
    int i = blockIdx.x * blockDim.x + threadIdx.x;
    if (i >= n4) return;
    f32x4 v = ((const f32x4*)src)[i];
    u16x4 o;
    o[0] = f2bf(v[0]); o[1] = f2bf(v[1]); o[2] = f2bf(v[2]); o[3] = f2bf(v[3]);
    *(u16x4*)(dst + (size_t)i * 4) = o;
}

// src is K x N (row-major f32), dst is N x K bf16
__global__ void k_transpose_bf16(const float* __restrict__ src, u16* __restrict__ dst, int K, int N) {
    __shared__ float tile[32][33];
    int n0 = blockIdx.x * 32, k0 = blockIdx.y * 32;
    int tx = threadIdx.x, ty = threadIdx.y;   // (32, 8)
#pragma unroll
    for (int i = 0; i < 4; i++)
        tile[ty + i * 8][tx] = src[(size_t)(k0 + ty + i * 8) * N + n0 + tx];
    __syncthreads();
#pragma unroll
    for (int i = 0; i < 4; i++) {
        int n = n0 + ty + i * 8;
        dst[(size_t)n * K + k0 + tx] = f2bf(tile[tx][ty + i * 8]);
    }
}

// per-head transpose: src [SEQ][HD] bf16 -> dst [HD][SEQ] bf16
__global__ void k_transpose_v(const u16* __restrict__ src, u16* __restrict__ dst) {
    __shared__ u16 tile[32][34];
    const u16* s = src + (size_t)blockIdx.z * SEQ * HD;
    u16* d = dst + (size_t)blockIdx.z * SEQ * HD;
    int d0 = blockIdx.x * 32;
    int s0 = blockIdx.y * 32;
    int tx = threadIdx.x, ty = threadIdx.y;   // (32, 8)
#pragma unroll
    for (int i = 0; i < 4; i++)
        tile[ty + i * 8][tx] = s[(size_t)(s0 + ty + i * 8) * HD + d0 + tx];
    __syncthreads();
#pragma unroll
    for (int i = 0; i < 4; i++)
        d[(size_t)(d0 + ty + i * 8) * SEQ + s0 + tx] = tile[tx][ty + i * 8];
}

__global__ void k_concat_bias(const float* __restrict__ bq, const float* __restrict__ bk,
                              const float* __restrict__ bv, float* __restrict__ out) {
    int i = blockIdx.x * blockDim.x + threadIdx.x;
    if (i >= NQKV) return;
    out[i] = (i < HID) ? bq[i] : (i < HID + 512 ? bk[i - HID] : bv[i - HID - 512]);
}

// ---------------- GEMM (m97 structure): C = A * BT^T + bias ----------------
// 128x128 tile, 4 waves, BK=32, global_load_lds width-16 staging, linear LDS.
template <int OUT_BF16>
__global__ __launch_bounds__(256) void k_gemm_bt(const u16* __restrict__ A, const u16* __restrict__ BT,
                                                 const float* __restrict__ bias, void* __restrict__ Cout,
                                                 int M, int N, int K, int lda, int ldb) {
    __shared__ u16 As[128 * 32];
    __shared__ u16 Bs[128 * 32];
    const int t = threadIdx.x;
    const int brow = blockIdx.y * 128, bcol = blockIdx.x * 128;
    const int wid = t >> 6, lane = t & 63;
    const int wr = (wid >> 1) * 64, wc = (wid & 1) * 64;
    const int lr = lane & 15;
    const int lk = (lane >> 4) * 8;

    // staging: wave `wid` issue i covers LDS bytes [(wid*2+i)*1024, +1024): lane -> base + lane*16
    const int srow0 = wid * 32 + (lane >> 2);     // row of issue 0
    const int scol = (lane & 3) * 8;              // elem col of the 16B chunk
    const u16* Ag0 = A + (size_t)(brow + srow0) * lda + scol;
    const u16* Ag1 = A + (size_t)(brow + srow0 + 16) * lda + scol;
    const u16* Bg0 = BT + (size_t)(bcol + srow0) * ldb + scol;
    const u16* Bg1 = BT + (size_t)(bcol + srow0 + 16) * ldb + scol;
    u16* Al0 = As + (wid * 2 + 0) * 512;
    u16* Al1 = As + (wid * 2 + 1) * 512;
    u16* Bl0 = Bs + (wid * 2 + 0) * 512;
    u16* Bl1 = Bs + (wid * 2 + 1) * 512;

    f32x4 acc[4][4] = {};
    for (int k0 = 0; k0 < K; k0 += 32) {
        __syncthreads();
        gload16(Ag0 + k0, Al0);
        gload16(Ag1 + k0, Al1);
        gload16(Bg0 + k0, Bl0);
        gload16(Bg1 + k0, Bl1);
        __syncthreads();   // compiler emits vmcnt(0) drain before barrier
        s16x8 af[4], bf[4];
#pragma unroll
        for (int mi = 0; mi < 4; mi++) af[mi] = *(const s16x8*)(As + (wr + mi * 16 + lr) * 32 + lk);
#pragma unroll
        for (int ni = 0; ni < 4; ni++) bf[ni] = *(const s16x8*)(Bs + (wc + ni * 16 + lr) * 32 + lk);
#pragma unroll
        for (int mi = 0; mi < 4; mi++)
#pragma unroll
            for (int ni = 0; ni < 4; ni++)
                acc[mi][ni] = __builtin_amdgcn_mfma_f32_16x16x32_bf16(af[mi], bf[ni], acc[mi][ni], 0, 0, 0);
    }

    const int drow = ((lane >> 4) << 2);
#pragma unroll
    for (int mi = 0; mi < 4; mi++) {
#pragma unroll
        for (int ni = 0; ni < 4; ni++) {
#pragma unroll
            for (int r = 0; r < 4; r++) {
                int row = brow + wr + mi * 16 + drow + r;
                int col = bcol + wc + ni * 16 + lr;
                float v = acc[mi][ni][r] + bias[col];
                if (OUT_BF16) ((u16*)Cout)[(size_t)row * N + col] = f2bf(v);
                else          ((float*)Cout)[(size_t)row * N + col] = v;
            }
        }
    }
}

// ---------------- RMSNorm + RoPE epilogue ----------------
__global__ __launch_bounds__(64) void k_norm_rope(const float* __restrict__ QKV,
                                                  const float* __restrict__ qn_w, const float* __restrict__ kn_w,
                                                  const float* __restrict__ cosT, const float* __restrict__ sinT,
                                                  u16* __restrict__ Qp, u16* __restrict__ Kp, u16* __restrict__ Vp) {
    int token = blockIdx.x;
    int slot = blockIdx.y;
    int d = threadIdx.x;
    int b = token >> 11, s = token & 2047;
    const float* row = QKV + (size_t)token * NQKV;
    if (slot < 40) {
        bool isq = slot < 32;
        int h = isq ? slot : slot - 32;
        float x = isq ? row[h * HD + d] : row[HID + h * HD + d];
        float ss = x * x;
#pragma unroll
        for (int o = 32; o; o >>= 1) ss += __shfl_xor(ss, o);
        float r = rsqrtf(ss * (1.0f / 64.0f) + 1e-6f);
        float xn = x * r * (isq ? qn_w[d] : kn_w[d]);
        float part = __shfl_xor(xn, 32);
        float sign = (d < 32) ? -1.f : 1.f;
        float o = xn * cosT[s * HD + d] + sign * part * sinT[s * HD + d];
        if (isq) Qp[(((size_t)(b * NH + h) * SEQ + s) * HD) + d] = f2bf(o);
        else     Kp[(((size_t)(b * NKV + h) * SEQ + s) * HD) + d] = f2bf(o);
    } else {
        int h = slot - 40;
        Vp[(((size_t)(b * NKV + h) * SEQ + s) * HD) + d] = f2bf(row[HID + 512 + h * HD + d]);
    }
}

// ---------------- MFMA flash attention (K/VT XOR-swizzled LDS) ----------------
__global__ __launch_bounds__(256) void k_attn_mfma(const u16* __restrict__ Qp, const u16* __restrict__ Kp,
                                                   const u16* __restrict__ VpT, u16* __restrict__ AO) {
    __shared__ u16 K_lds[64 * 64];    // [row][64] linear, 16B-slot XOR swizzle by (row&7)
    __shared__ u16 VT_lds[64 * 64];
    __shared__ u16 P_lds[4][32][76];
    const int bid = blockIdx.x;
    const int qt = 15 - (bid >> 6);        // heavy tiles dispatched first
    const int hh = bid & 63;
    const int b = hh >> 5, h = hh & 31, kvh = h >> 2;
    const int t = threadIdx.x, w = t >> 6, lane = t & 63;
    const int lr = lane & 15, g = lane >> 4;
    const int qb = qt * 128 + w * 32;

    const u16* Qb = Qp + (size_t)(b * NH + h) * SEQ * HD;
    const u16* Kb = Kp + (size_t)(b * NKV + kvh) * SEQ * HD;
    const u16* Vb = VpT + (size_t)(b * NKV + kvh) * HD * SEQ;

    // hoist Q fragments (A-operand: row = lr, k = 32*ks + 8*g + j)
    s16x8 aq[2][2];
#pragma unroll
    for (int mi = 0; mi < 2; mi++)
#pragma unroll
        for (int ks = 0; ks < 2; ks++)
            aq[mi][ks] = *(const s16x8*)(Qb + (size_t)(qb + mi * 16 + lr) * HD + ks * 32 + g * 8);

    f32x4 O[2][4];
    float m[2][4], l[2][4];
#pragma unroll
    for (int mi = 0; mi < 2; mi++)
#pragma unroll
        for (int x = 0; x < 4; x++) { O[mi][x] = (f32x4){0.f, 0.f, 0.f, 0.f}; m[mi][x] = -1e30f; l[mi][x] = 0.f; }

    const int swz = (lr & 7) << 4;       // read-side XOR (row&7 == lr&7 for 16-aligned row blocks)
    const int nkt = 2 * (qt + 1);
    for (int kt = 0; kt < nkt; kt++) {
        const int k0 = kt * 64;
        __syncthreads();
#pragma unroll
        for (int i = 0; i < 2; i++) {
            int c = t + 256 * i;
            int row = c >> 3, slot = c & 7;
            int colb = (slot * 16) ^ ((row & 7) << 4);
            *(u16x8*)((char*)K_lds + row * 128 + colb)  = *(const u16x8*)(Kb + (size_t)(k0 + row) * HD + slot * 8);
            *(u16x8*)((char*)VT_lds + row * 128 + colb) = *(const u16x8*)(Vb + (size_t)row * SEQ + k0 + slot * 8);
        }
        __syncthreads();
        if (k0 > qb + 31) continue;     // wave-uniform skip; no barrier inside

        // ---- S = Q K^T ----
        f32x4 s[2][4];
#pragma unroll
        for (int mi = 0; mi < 2; mi++)
#pragma unroll
            for (int ni = 0; ni < 4; ni++) s[mi][ni] = (f32x4){0.f, 0.f, 0.f, 0.f};
#pragma unroll
        for (int ni = 0; ni < 4; ni++) {
            s16x8 bk0 = *(const s16x8*)((const char*)K_lds + (ni * 16 + lr) * 128 + ((g * 16) ^ swz));
            s16x8 bk1 = *(const s16x8*)((const char*)K_lds + (ni * 16 + lr) * 128 + ((64 + g * 16) ^ swz));
#pragma unroll
            for (int mi = 0; mi < 2; mi++) {
                s[mi][ni] = __builtin_amdgcn_mfma_f32_16x16x32_bf16(aq[mi][0], bk0, s[mi][ni], 0, 0, 0);
                s[mi][ni] = __builtin_amdgcn_mfma_f32_16x16x32_bf16(aq[mi][1], bk1, s[mi][ni], 0, 0, 0);
            }
        }

        const bool diag = (k0 + 63 > qb);
#pragma unroll
        for (int mi = 0; mi < 2; mi++)
#pragma unroll
            for (int ni = 0; ni < 4; ni++)
#pragma unroll
                for (int r = 0; r < 4; r++) {
                    float v = s[mi][ni][r] * 0.125f;
                    if (diag && (k0 + ni * 16 + lr > qb + mi * 16 + 4 * g + r)) v = -1e30f;
                    s[mi][ni][r] = v;
                }

        // ---- online softmax (per q-row; row spans the 16-lane col group) ----
#pragma unroll
        for (int mi = 0; mi < 2; mi++) {
#pragma unroll
            for (int r = 0; r < 4; r++) {
                float pm = fmaxf(fmaxf(s[mi][0][r], s[mi][1][r]), fmaxf(s[mi][2][r], s[mi][3][r]));
#pragma unroll
                for (int off = 1; off < 16; off <<= 1) pm = fmaxf(pm, __shfl_xor(pm, off));
                float mn = fmaxf(m[mi][r], pm);
                float f = __expf(m[mi][r] - mn);
                m[mi][r] = mn;
                float ps = 0.f;
#pragma unroll
                for (int ni = 0; ni < 4; ni++) {
                    float p = __expf(s[mi][ni][r] - mn);
                    s[mi][ni][r] = p;
                    ps += p;
                }
#pragma unroll
                for (int off = 1; off < 16; off <<= 1) ps += __shfl_xor(ps, off);
                l[mi][r] = l[mi][r] * f + ps;
#pragma unroll
                for (int nd = 0; nd < 4; nd++) O[mi][nd][r] *= f;
            }
        }

        // ---- P (C-layout) -> LDS -> A-layout ----
#pragma unroll
        for (int mi = 0; mi < 2; mi++)
#pragma unroll
            for (int ni = 0; ni < 4; ni++)
#pragma unroll
                for (int r = 0; r < 4; r++)
                    P_lds[w][mi * 16 + 4 * g + r][ni * 16 + lr] = f2bf(s[mi][ni][r]);

        // ---- O += P V ----
#pragma unroll
        for (int ks = 0; ks < 2; ks++) {
            s16x8 pa0 = *(const s16x8*)&P_lds[w][lr][ks * 32 + g * 8];
            s16x8 pa1 = *(const s16x8*)&P_lds[w][16 + lr][ks * 32 + g * 8];
#pragma unroll
            for (int nd = 0; nd < 4; nd++) {
                s16x8 vb = *(const s16x8*)((const char*)VT_lds + (nd * 16 + lr) * 128 + ((ks * 64 + g * 16) ^ swz));
                O[0][nd] = __builtin_amdgcn_mfma_f32_16x16x32_bf16(pa0, vb, O[0][nd], 0, 0, 0);
                O[1][nd] = __builtin_amdgcn_mfma_f32_16x16x32_bf16(pa1, vb, O[1][nd], 0, 0, 0);
            }
        }
    }

    // ---- epilogue: O/l -> AO[tok][h*64+d] bf16 ----
#pragma unroll
    for (int mi = 0; mi < 2; mi++) {
#pragma unroll
        for (int r = 0; r < 4; r++) {
            float inv = 1.0f / l[mi][r];
            int q = qb + mi * 16 + 4 * g + r;
            u16* orow = AO + (size_t)(b * SEQ + q) * (NH * HD) + h * HD;
#pragma unroll
            for (int nd = 0; nd < 4; nd++)
                orow[nd * 16 + lr] = f2bf(O[mi][nd][r] * inv);
        }
    }
}

// ---------------- launch ----------------
extern "C" void kernel_launch(void* const* d_in, const int* in_sizes, int n_in,
                              void* d_out, int out_size, void* d_ws, size_t ws_size,
                              hipStream_t stream) {
    const float* hs   = (const float*)d_in[0];
    const float* Wq   = (const float*)d_in[1];
    const float* bq   = (const float*)d_in[2];
    const float* Wk   = (const float*)d_in[3];
    const float* bk   = (const float*)d_in[4];
    const float* Wv   = (const float*)d_in[5];
    const float* bv   = (const float*)d_in[6];
    const float* Wo   = (const float*)d_in[7];
    const float* bo   = (const float*)d_in[8];
    const float* qn_w = (const float*)d_in[9];
    const float* kn_w = (const float*)d_in[10];
    const float* cosT = (const float*)d_in[11];
    const float* sinT = (const float*)d_in[12];

    char* ws = (char*)d_ws;
    size_t off = 0;
    auto alloc = [&](size_t bytes) { char* p = ws + off; off = (off + bytes + 255) & ~(size_t)255; return p; };
    u16*   Xb    = (u16*)  alloc((size_t)TOK * HID * 2);
    u16*   WTqkv = (u16*)  alloc((size_t)NQKV * HID * 2);
    u16*   WoT   = (u16*)  alloc((size_t)HID * HID * 2);
    float* bqkv  = (float*)alloc((size_t)NQKV * 4);
    float* QKV   = (float*)alloc((size_t)TOK * NQKV * 4);
    u16*   Qp    = (u16*)  alloc((size_t)BATCH * NH * SEQ * HD * 2);
    u16*   Kp    = (u16*)  alloc((size_t)BATCH * NKV * SEQ * HD * 2);
    u16*   Vp    = (u16*)  alloc((size_t)BATCH * NKV * SEQ * HD * 2);
    u16*   VpT   = (u16*)  alloc((size_t)BATCH * NKV * SEQ * HD * 2);
    u16*   AO    = (u16*)  alloc((size_t)TOK * HID * 2);
    (void)ws_size;

    k_f32_to_bf16<<<(TOK * HID / 4 + 255) / 256, 256, 0, stream>>>(hs, Xb, TOK * HID / 4);
    dim3 tb(32, 8);
    k_transpose_bf16<<<dim3(HID / 32, HID / 32), tb, 0, stream>>>(Wq, WTqkv, HID, HID);
    k_transpose_bf16<<<dim3(512 / 32, HID / 32), tb, 0, stream>>>(Wk, WTqkv + (size_t)HID * HID, HID, 512);
    k_transpose_bf16<<<dim3(512 / 32, HID / 32), tb, 0, stream>>>(Wv, WTqkv + (size_t)(HID + 512) * HID, HID, 512);
    k_transpose_bf16<<<dim3(HID / 32, HID / 32), tb, 0, stream>>>(Wo, WoT, HID, HID);
    k_concat_bias<<<(NQKV + 255) / 256, 256, 0, stream>>>(bq, bk, bv, bqkv);
    // QKV GEMM -> f32
    k_gemm_bt<0><<<dim3(NQKV / 128, TOK / 128), 256, 0, stream>>>(Xb, WTqkv, bqkv, QKV, TOK, NQKV, HID, HID, HID);
    // norm + rope
    k_norm_rope<<<dim3(TOK, 48), 64, 0, stream>>>(QKV, qn_w, kn_w, cosT, sinT, Qp, Kp, Vp);
    // V transpose per head: [SEQ][HD] -> [HD][SEQ]
    k_transpose_v<<<dim3(HD / 32, SEQ / 32, BATCH * NKV), tb, 0, stream>>>(Vp, VpT);
    // MFMA flash attention
    k_attn_mfma<<<BATCH * NH * (SEQ / 128), 256, 0, stream>>>(Qp, Kp, VpT, AO);
    // output projection -> f32 d_out
    k_gemm_bt<0><<<dim3(HID / 128, TOK / 128), 256, 0, stream>>>(AO, WoT, bo, d_out, TOK, HID, HID, HID, HID);
}

// Round 8
// 274.305 us; speedup vs baseline: 7.6007x; 1.1531x over previous
//
#include <hip/hip_runtime.h>

typedef unsigned short u16;
typedef __attribute__((ext_vector_type(4))) float f32x4;
typedef __attribute__((ext_vector_type(16))) float f32x16;
typedef __attribute__((ext_vector_type(8))) short s16x8;
typedef __attribute__((ext_vector_type(8))) unsigned short u16x8;
typedef __attribute__((ext_vector_type(4))) unsigned short u16x4;

__device__ __forceinline__ float bf2f(u16 u) {
    union { unsigned int i; float f; } x; x.i = ((unsigned int)u) << 16; return x.f;
}
__device__ __forceinline__ u16 f2bf(float f) {
    union { float f; unsigned int i; } x; x.f = f;
    unsigned int r = x.i + 0x7FFFu + ((x.i >> 16) & 1u);
    return (u16)(r >> 16);
}
__device__ __forceinline__ void gload16(const void* g, void* l) {
    __builtin_amdgcn_global_load_lds((const __attribute__((address_space(1))) void*)g,
                                     (__attribute__((address_space(3))) void*)l, 16, 0, 0);
}
__device__ __forceinline__ unsigned cvtpk(float lo, float hi) {
    unsigned r;
    asm("v_cvt_pk_bf16_f32 %0, %1, %2" : "=v"(r) : "v"(lo), "v"(hi));
    return r;
}

// ---------------- constants ----------------
#define BATCH 2
#define SEQ 2048
#define HID 2048
#define NH 32
#define NKV 8
#define HD 64
#define TOK (BATCH * SEQ)
#define NQKV 3072
#define QSCALE 0.18033688011112042f   // 0.125 * log2(e), folded into Q

// ---------------- pre-pass kernels (device data is f32) ----------------
__global__ void k_f32_to_bf16(const float* __restrict__ src, u16* __restrict__ dst, int n4) {
    int i = blockIdx.x * blockDim.x + threadIdx.x;
    if (i >= n4) return;
    f32x4 v = ((const f32x4*)src)[i];
    u16x4 o;
    o[0] = f2bf(v[0]); o[1] = f2bf(v[1]); o[2] = f2bf(v[2]); o[3] = f2bf(v[3]);
    *(u16x4*)(dst + (size_t)i * 4) = o;
}

__global__ void k_transpose_bf16(const float* __restrict__ src, u16* __restrict__ dst, int K, int N) {
    __shared__ float tile[32][33];
    int n0 = blockIdx.x * 32, k0 = blockIdx.y * 32;
    int tx = threadIdx.x, ty = threadIdx.y;
#pragma unroll
    for (int i = 0; i < 4; i++)
        tile[ty + i * 8][tx] = src[(size_t)(k0 + ty + i * 8) * N + n0 + tx];
    __syncthreads();
#pragma unroll
    for (int i = 0; i < 4; i++) {
        int n = n0 + ty + i * 8;
        dst[(size_t)n * K + k0 + tx] = f2bf(tile[tx][ty + i * 8]);
    }
}

// per-head transpose: src [SEQ][HD] bf16 -> dst [HD][SEQ] bf16 (plain)
__global__ void k_transpose_v(const u16* __restrict__ src, u16* __restrict__ dst) {
    __shared__ u16 tile[32][34];
    const u16* s = src + (size_t)blockIdx.z * SEQ * HD;
    u16* d = dst + (size_t)blockIdx.z * SEQ * HD;
    int d0 = blockIdx.x * 32;
    int s0 = blockIdx.y * 32;
    int tx = threadIdx.x, ty = threadIdx.y;
#pragma unroll
    for (int i = 0; i < 4; i++)
        tile[ty + i * 8][tx] = s[(size_t)(s0 + ty + i * 8) * HD + d0 + tx];
    __syncthreads();
#pragma unroll
    for (int i = 0; i < 4; i++)
        d[(size_t)(d0 + ty + i * 8) * SEQ + s0 + tx] = tile[tx][ty + i * 8];
}

__global__ void k_concat_bias(const float* __restrict__ bq, const float* __restrict__ bk,
                              const float* __restrict__ bv, float* __restrict__ out) {
    int i = blockIdx.x * blockDim.x + threadIdx.x;
    if (i >= NQKV) return;
    out[i] = (i < HID) ? bq[i] : (i < HID + 512 ? bk[i - HID] : bv[i - HID - 512]);
}

// ---------------- GEMM (m97 structure) ----------------
template <int OUT_BF16>
__global__ __launch_bounds__(256) void k_gemm_bt(const u16* __restrict__ A, const u16* __restrict__ BT,
                                                 const float* __restrict__ bias, void* __restrict__ Cout,
                                                 int M, int N, int K, int lda, int ldb) {
    __shared__ u16 As[128 * 32];
    __shared__ u16 Bs[128 * 32];
    const int t = threadIdx.x;
    const int brow = blockIdx.y * 128, bcol = blockIdx.x * 128;
    const int wid = t >> 6, lane = t & 63;
    const int wr = (wid >> 1) * 64, wc = (wid & 1) * 64;
    const int lr = lane & 15;
    const int lk = (lane >> 4) * 8;

    const int srow0 = wid * 32 + (lane >> 2);
    const int scol = (lane & 3) * 8;
    const u16* Ag0 = A + (size_t)(brow + srow0) * lda + scol;
    const u16* Ag1 = A + (size_t)(brow + srow0 + 16) * lda + scol;
    const u16* Bg0 = BT + (size_t)(bcol + srow0) * ldb + scol;
    const u16* Bg1 = BT + (size_t)(bcol + srow0 + 16) * ldb + scol;
    u16* Al0 = As + (wid * 2 + 0) * 512;
    u16* Al1 = As + (wid * 2 + 1) * 512;
    u16* Bl0 = Bs + (wid * 2 + 0) * 512;
    u16* Bl1 = Bs + (wid * 2 + 1) * 512;

    f32x4 acc[4][4] = {};
    for (int k0 = 0; k0 < K; k0 += 32) {
        __syncthreads();
        gload16(Ag0 + k0, Al0);
        gload16(Ag1 + k0, Al1);
        gload16(Bg0 + k0, Bl0);
        gload16(Bg1 + k0, Bl1);
        __syncthreads();
        s16x8 af[4], bf[4];
#pragma unroll
        for (int mi = 0; mi < 4; mi++) af[mi] = *(const s16x8*)(As + (wr + mi * 16 + lr) * 32 + lk);
#pragma unroll
        for (int ni = 0; ni < 4; ni++) bf[ni] = *(const s16x8*)(Bs + (wc + ni * 16 + lr) * 32 + lk);
#pragma unroll
        for (int mi = 0; mi < 4; mi++)
#pragma unroll
            for (int ni = 0; ni < 4; ni++)
                acc[mi][ni] = __builtin_amdgcn_mfma_f32_16x16x32_bf16(af[mi], bf[ni], acc[mi][ni], 0, 0, 0);
    }

    const int drow = ((lane >> 4) << 2);
#pragma unroll
    for (int mi = 0; mi < 4; mi++) {
#pragma unroll
        for (int ni = 0; ni < 4; ni++) {
#pragma unroll
            for (int r = 0; r < 4; r++) {
                int row = brow + wr + mi * 16 + drow + r;
                int col = bcol + wc + ni * 16 + lr;
                float v = acc[mi][ni][r] + bias[col];
                if (OUT_BF16) ((u16*)Cout)[(size_t)row * N + col] = f2bf(v);
                else          ((float*)Cout)[(size_t)row * N + col] = v;
            }
        }
    }
}

// ---------------- RMSNorm + RoPE (Q pre-scaled by 0.125*log2e) ----------------
__global__ __launch_bounds__(64) void k_norm_rope(const float* __restrict__ QKV,
                                                  const float* __restrict__ qn_w, const float* __restrict__ kn_w,
                                                  const float* __restrict__ cosT, const float* __restrict__ sinT,
                                                  u16* __restrict__ Qp, u16* __restrict__ Kp, u16* __restrict__ Vp) {
    int token = blockIdx.x;
    int slot = blockIdx.y;
    int d = threadIdx.x;
    int b = token >> 11, s = token & 2047;
    const float* row = QKV + (size_t)token * NQKV;
    if (slot < 40) {
        bool isq = slot < 32;
        int h = isq ? slot : slot - 32;
        float x = isq ? row[h * HD + d] : row[HID + h * HD + d];
        float ss = x * x;
#pragma unroll
        for (int o = 32; o; o >>= 1) ss += __shfl_xor(ss, o);
        float r = rsqrtf(ss * (1.0f / 64.0f) + 1e-6f);
        float xn = x * r * (isq ? qn_w[d] : kn_w[d]);
        float part = __shfl_xor(xn, 32);
        float sign = (d < 32) ? -1.f : 1.f;
        float o = xn * cosT[s * HD + d] + sign * part * sinT[s * HD + d];
        if (isq) Qp[(((size_t)(b * NH + h) * SEQ + s) * HD) + d] = f2bf(o * QSCALE);
        else     Kp[(((size_t)(b * NKV + h) * SEQ + s) * HD) + d] = f2bf(o);
    } else {
        int h = slot - 40;
        Vp[(((size_t)(b * NKV + h) * SEQ + s) * HD) + d] = f2bf(row[HID + 512 + h * HD + d]);
    }
}

// ---------------- MFMA flash attention v4 ----------------
// 4 warps x 32 q-rows, 32x32x16 MFMA, swapped operands (S^T, O^T),
// in-register softmax (lane pair owns one q-row), P via per-wave LDS
// round-trip in [q][key] layout (both PV operands memory-loaded -> any
// fragment-map mismatch cancels).
__global__ __launch_bounds__(256) void k_attn_mfma(const u16* __restrict__ Qp, const u16* __restrict__ Kp,
                                                   const u16* __restrict__ VpT, u16* __restrict__ AO) {
    __shared__ u16 K_lds[64 * 64];    // [key][d], 16B slots XOR'd by key&7
    __shared__ u16 VT_lds[64 * 64];   // [d][key], 16B slots XOR'd by d&7
    __shared__ u16 P_lds[4][32][72];  // per-wave, [q][key], pad to 72
    const int bid = blockIdx.x;
    const int qt = 15 - (bid >> 6);   // heavy tiles first
    const int hh = bid & 63;
    const int b = hh >> 5, h = hh & 31, kvh = h >> 2;
    const int t = threadIdx.x, w = t >> 6, lane = t & 63;
    const int q5 = lane & 31, hi = lane >> 5;
    const int qwb = qt * 128 + w * 32;
    const int q_abs = qwb + q5;

    const u16* Qb = Qp + (size_t)(b * NH + h) * SEQ * HD;
    const u16* Kb = Kp + (size_t)(b * NKV + kvh) * SEQ * HD;
    const u16* Vb = VpT + (size_t)(b * NKV + kvh) * HD * SEQ;

    // Q as B-operand: frag[dblk] elem j -> d = dblk*16 + 8*hi + j
    s16x8 qf0 = *(const s16x8*)(Qb + (size_t)q_abs * HD + 0 * 16 + hi * 8);
    s16x8 qf1 = *(const s16x8*)(Qb + (size_t)q_abs * HD + 1 * 16 + hi * 8);
    s16x8 qf2 = *(const s16x8*)(Qb + (size_t)q_abs * HD + 2 * 16 + hi * 8);
    s16x8 qf3 = *(const s16x8*)(Qb + (size_t)q_abs * HD + 3 * 16 + hi * 8);

    f32x16 O0, O1;
#pragma unroll
    for (int r = 0; r < 16; r++) { O0[r] = 0.f; O1[r] = 0.f; }
    float m = -1e30f, l = 0.f;

    const int swz = (q5 & 7) << 4;
    const int nkt = 2 * (qt + 1);
    for (int kt = 0; kt < nkt; kt++) {
        const int k0 = kt * 64;
        __syncthreads();
#pragma unroll
        for (int i = 0; i < 2; i++) {
            int c = (w * 2 + i) * 64 + lane;
            int row = c >> 3, gslot = (c & 7) ^ (row & 7);
            gload16(Kb + (size_t)(k0 + row) * HD + gslot * 8, (char*)K_lds + (size_t)(w * 2 + i) * 1024);
            gload16(Vb + (size_t)row * SEQ + k0 + gslot * 8, (char*)VT_lds + (size_t)(w * 2 + i) * 1024);
        }
        __syncthreads();
        if (k0 > qwb + 31) continue;   // wave-uniform; no barrier below

        // ---- S^T = K Q^T : lane holds q-row q5, keys (r&3)+8*(r>>2)+4*hi (+32 for s1)
        f32x16 s0, s1;
#pragma unroll
        for (int r = 0; r < 16; r++) { s0[r] = 0.f; s1[r] = 0.f; }
#pragma unroll
        for (int dblk = 0; dblk < 4; dblk++) {
            s16x8 kf0 = *(const s16x8*)((const char*)K_lds + q5 * 128 + ((dblk * 32 + hi * 16) ^ swz));
            s16x8 kf1 = *(const s16x8*)((const char*)K_lds + (32 + q5) * 128 + ((dblk * 32 + hi * 16) ^ swz));
            s16x8 qq = (dblk == 0) ? qf0 : (dblk == 1) ? qf1 : (dblk == 2) ? qf2 : qf3;
            s0 = __builtin_amdgcn_mfma_f32_32x32x16_bf16(kf0, qq, s0, 0, 0, 0);
            s1 = __builtin_amdgcn_mfma_f32_32x32x16_bf16(kf1, qq, s1, 0, 0, 0);
        }

        if (k0 + 63 > qwb) {            // FIXED: diagonal if tile has keys > min q in wave
            const int qrel = q_abs - k0;
#pragma unroll
            for (int r = 0; r < 16; r++) {
                int kr = (r & 3) + 8 * (r >> 2) + 4 * hi;
                if (kr > qrel) s0[r] = -1e30f;
                if (kr + 32 > qrel) s1[r] = -1e30f;
            }
        }

        // ---- online softmax, log2 domain (scale folded into Q) ----
        float mt = -1e30f;
#pragma unroll
        for (int r = 0; r < 16; r++) { mt = fmaxf(mt, s0[r]); mt = fmaxf(mt, s1[r]); }
        mt = fmaxf(mt, __shfl_xor(mt, 32));   // pair-reduce: rescues fully-masked lanes
        if (!__all(mt <= m + 8.0f)) {   // defer-max (T13)
            float mn = fmaxf(m, mt);
            float f = exp2f(m - mn);
            l *= f;
#pragma unroll
            for (int r = 0; r < 16; r++) { O0[r] *= f; O1[r] *= f; }
            m = mn;
        }
        float ps = 0.f;
#pragma unroll
        for (int r = 0; r < 16; r++) {
            float p0 = exp2f(s0[r] - m);
            float p1 = exp2f(s1[r] - m);
            s0[r] = p0; s1[r] = p1;
            ps += p0 + p1;
        }
        ps += __shfl_xor(ps, 32);
        l += ps;

        // ---- P -> per-wave LDS [q][key] (C-layout keys are verified) ----
#pragma unroll
        for (int i = 0; i < 8; i++) {
            int key = 2 * (i & 1) + 8 * (i >> 1) + 4 * hi;   // keys of s[2i],s[2i+1] (adjacent)
            *(unsigned*)&P_lds[w][q5][key]      = cvtpk(s0[2 * i], s0[2 * i + 1]);
            *(unsigned*)&P_lds[w][q5][key + 32] = cvtpk(s1[2 * i], s1[2 * i + 1]);
        }

        // ---- O^T += V^T P^T : both operands loaded with the same assumed map ----
#pragma unroll
        for (int ks = 0; ks < 4; ks++) {
            s16x8 pb  = *(const s16x8*)&P_lds[w][q5][ks * 16 + hi * 8];
            s16x8 vf0 = *(const s16x8*)((const char*)VT_lds + q5 * 128 + ((ks * 32 + hi * 16) ^ swz));
            s16x8 vf1 = *(const s16x8*)((const char*)VT_lds + (32 + q5) * 128 + ((ks * 32 + hi * 16) ^ swz));
            O0 = __builtin_amdgcn_mfma_f32_32x32x16_bf16(vf0, pb, O0, 0, 0, 0);
            O1 = __builtin_amdgcn_mfma_f32_32x32x16_bf16(vf1, pb, O1, 0, 0, 0);
        }
    }

    // ---- epilogue: lane owns q-row q_abs; d = 32*db + 8*g2 + 4*hi + i2 ----
    float inv = 1.0f / l;
    u16* orow = AO + (size_t)(b * SEQ + q_abs) * (NH * HD) + h * HD;
#pragma unroll
    for (int db = 0; db < 2; db++) {
#pragma unroll
        for (int g2 = 0; g2 < 4; g2++) {
            u16x4 wv;
#pragma unroll
            for (int i2 = 0; i2 < 4; i2++) {
                float v = (db == 0 ? O0[g2 * 4 + i2] : O1[g2 * 4 + i2]) * inv;
                wv[i2] = f2bf(v);
            }
            *(u16x4*)(orow + db * 32 + g2 * 8 + hi * 4) = wv;
        }
    }
}

// ---------------- launch ----------------
extern "C" void kernel_launch(void* const* d_in, const int* in_sizes, int n_in,
                              void* d_out, int out_size, void* d_ws, size_t ws_size,
                              hipStream_t stream) {
    const float* hs   = (const float*)d_in[0];
    const float* Wq   = (const float*)d_in[1];
    const float* bq   = (const float*)d_in[2];
    const float* Wk   = (const float*)d_in[3];
    const float* bk   = (const float*)d_in[4];
    const float* Wv   = (const float*)d_in[5];
    const float* bv   = (const float*)d_in[6];
    const float* Wo   = (const float*)d_in[7];
    const float* bo   = (const float*)d_in[8];
    const float* qn_w = (const float*)d_in[9];
    const float* kn_w = (const float*)d_in[10];
    const float* cosT = (const float*)d_in[11];
    const float* sinT = (const float*)d_in[12];

    char* ws = (char*)d_ws;
    size_t off = 0;
    auto alloc = [&](size_t bytes) { char* p = ws + off; off = (off + bytes + 255) & ~(size_t)255; return p; };
    u16*   Xb    = (u16*)  alloc((size_t)TOK * HID * 2);
    u16*   WTqkv = (u16*)  alloc((size_t)NQKV * HID * 2);
    u16*   WoT   = (u16*)  alloc((size_t)HID * HID * 2);
    float* bqkv  = (float*)alloc((size_t)NQKV * 4);
    float* QKV   = (float*)alloc((size_t)TOK * NQKV * 4);
    u16*   Qp    = (u16*)  alloc((size_t)BATCH * NH * SEQ * HD * 2);
    u16*   Kp    = (u16*)  alloc((size_t)BATCH * NKV * SEQ * HD * 2);
    u16*   Vp    = (u16*)  alloc((size_t)BATCH * NKV * SEQ * HD * 2);
    u16*   VpT   = (u16*)  alloc((size_t)BATCH * NKV * SEQ * HD * 2);
    u16*   AO    = (u16*)  alloc((size_t)TOK * HID * 2);
    (void)ws_size;

    k_f32_to_bf16<<<(TOK * HID / 4 + 255) / 256, 256, 0, stream>>>(hs, Xb, TOK * HID / 4);
    dim3 tb(32, 8);
    k_transpose_bf16<<<dim3(HID / 32, HID / 32), tb, 0, stream>>>(Wq, WTqkv, HID, HID);
    k_transpose_bf16<<<dim3(512 / 32, HID / 32), tb, 0, stream>>>(Wk, WTqkv + (size_t)HID * HID, HID, 512);
    k_transpose_bf16<<<dim3(512 / 32, HID / 32), tb, 0, stream>>>(Wv, WTqkv + (size_t)(HID + 512) * HID, HID, 512);
    k_transpose_bf16<<<dim3(HID / 32, HID / 32), tb, 0, stream>>>(Wo, WoT, HID, HID);
    k_concat_bias<<<(NQKV + 255) / 256, 256, 0, stream>>>(bq, bk, bv, bqkv);
    // QKV GEMM -> f32
    k_gemm_bt<0><<<dim3(NQKV / 128, TOK / 128), 256, 0, stream>>>(Xb, WTqkv, bqkv, QKV, TOK, NQKV, HID, HID, HID);
    // norm + rope
    k_norm_rope<<<dim3(TOK, 48), 64, 0, stream>>>(QKV, qn_w, kn_w, cosT, sinT, Qp, Kp, Vp);
    // V transpose per head
    k_transpose_v<<<dim3(HD / 32, SEQ / 32, BATCH * NKV), tb, 0, stream>>>(Vp, VpT);
    // MFMA flash attention v4
    k_attn_mfma<<<BATCH * NH * (SEQ / 128), 256, 0, stream>>>(Qp, Kp, VpT, AO);
    // output projection -> f32 d_out
    k_gemm_bt<0><<<dim3(HID / 128, TOK / 128), 256, 0, stream>>>(AO, WoT, bo, d_out, TOK, HID, HID, HID, HID);
}

// Round 9
// 269.431 us; speedup vs baseline: 7.7382x; 1.0181x over previous
//
#include <hip/hip_runtime.h>

typedef unsigned short u16;
typedef __attribute__((ext_vector_type(4))) float f32x4;
typedef __attribute__((ext_vector_type(16))) float f32x16;
typedef __attribute__((ext_vector_type(8))) short s16x8;
typedef __attribute__((ext_vector_type(8))) unsigned short u16x8;
typedef __attribute__((ext_vector_type(4))) unsigned short u16x4;

__device__ __forceinline__ float bf2f(u16 u) {
    union { unsigned int i; float f; } x; x.i = ((unsigned int)u) << 16; return x.f;
}
__device__ __forceinline__ u16 f2bf(float f) {
    union { float f; unsigned int i; } x; x.f = f;
    unsigned int r = x.i + 0x7FFFu + ((x.i >> 16) & 1u);
    return (u16)(r >> 16);
}
__device__ __forceinline__ void gload16(const void* g, void* l) {
    __builtin_amdgcn_global_load_lds((const __attribute__((address_space(1))) void*)g,
                                     (__attribute__((address_space(3))) void*)l, 16, 0, 0);
}
__device__ __forceinline__ unsigned cvtpk(float lo, float hi) {
    unsigned r;
    asm("v_cvt_pk_bf16_f32 %0, %1, %2" : "=v"(r) : "v"(lo), "v"(hi));
    return r;
}

// ---------------- constants ----------------
#define BATCH 2
#define SEQ 2048
#define HID 2048
#define NH 32
#define NKV 8
#define HD 64
#define TOK (BATCH * SEQ)
#define NQKV 3072
#define QSCALE 0.18033688011112042f   // 0.125 * log2(e), folded into Q

// ---------------- pre-pass kernels (device data is f32) ----------------
__global__ void k_f32_to_bf16(const float* __restrict__ src, u16* __restrict__ dst, int n4) {
    int i = blockIdx.x * blockDim.x + threadIdx.x;
    if (i >= n4) return;
    f32x4 v = ((const f32x4*)src)[i];
    u16x4 o;
    o[0] = f2bf(v[0]); o[1] = f2bf(v[1]); o[2] = f2bf(v[2]); o[3] = f2bf(v[3]);
    *(u16x4*)(dst + (size_t)i * 4) = o;
}

__global__ void k_transpose_bf16(const float* __restrict__ src, u16* __restrict__ dst, int K, int N) {
    __shared__ float tile[32][33];
    int n0 = blockIdx.x * 32, k0 = blockIdx.y * 32;
    int tx = threadIdx.x, ty = threadIdx.y;
#pragma unroll
    for (int i = 0; i < 4; i++)
        tile[ty + i * 8][tx] = src[(size_t)(k0 + ty + i * 8) * N + n0 + tx];
    __syncthreads();
#pragma unroll
    for (int i = 0; i < 4; i++) {
        int n = n0 + ty + i * 8;
        dst[(size_t)n * K + k0 + tx] = f2bf(tile[tx][ty + i * 8]);
    }
}

// per-head transpose: src [SEQ][HD] bf16 -> dst [HD][SEQ] bf16 (plain)
__global__ void k_transpose_v(const u16* __restrict__ src, u16* __restrict__ dst) {
    __shared__ u16 tile[32][34];
    const u16* s = src + (size_t)blockIdx.z * SEQ * HD;
    u16* d = dst + (size_t)blockIdx.z * SEQ * HD;
    int d0 = blockIdx.x * 32;
    int s0 = blockIdx.y * 32;
    int tx = threadIdx.x, ty = threadIdx.y;
#pragma unroll
    for (int i = 0; i < 4; i++)
        tile[ty + i * 8][tx] = s[(size_t)(s0 + ty + i * 8) * HD + d0 + tx];
    __syncthreads();
#pragma unroll
    for (int i = 0; i < 4; i++)
        d[(size_t)(d0 + ty + i * 8) * SEQ + s0 + tx] = tile[tx][ty + i * 8];
}

__global__ void k_concat_bias(const float* __restrict__ bq, const float* __restrict__ bk,
                              const float* __restrict__ bv, float* __restrict__ out) {
    int i = blockIdx.x * blockDim.x + threadIdx.x;
    if (i >= NQKV) return;
    out[i] = (i < HID) ? bq[i] : (i < HID + 512 ? bk[i - HID] : bv[i - HID - 512]);
}

// ---------------- GEMM (m97 structure + XCD-bijective swizzle) ----------------
// grid must satisfy (gridDim.x*gridDim.y) % 8 == 0.
template <int OUT_BF16>
__global__ __launch_bounds__(256) void k_gemm_bt(const u16* __restrict__ A, const u16* __restrict__ BT,
                                                 const float* __restrict__ bias, void* __restrict__ Cout,
                                                 int M, int N, int K, int lda, int ldb) {
    __shared__ u16 As[128 * 32];
    __shared__ u16 Bs[128 * 32];
    const int t = threadIdx.x;
    const int gx = gridDim.x;
    int bid = blockIdx.y * gx + blockIdx.x;
    const int cpx = (gx * gridDim.y) >> 3;
    bid = (bid & 7) * cpx + (bid >> 3);          // XCD gets contiguous tile chunk
    const int brow = (bid / gx) * 128, bcol = (bid % gx) * 128;
    const int wid = t >> 6, lane = t & 63;
    const int wr = (wid >> 1) * 64, wc = (wid & 1) * 64;
    const int lr = lane & 15;
    const int lk = (lane >> 4) * 8;

    const int srow0 = wid * 32 + (lane >> 2);
    const int scol = (lane & 3) * 8;
    const u16* Ag0 = A + (size_t)(brow + srow0) * lda + scol;
    const u16* Ag1 = A + (size_t)(brow + srow0 + 16) * lda + scol;
    const u16* Bg0 = BT + (size_t)(bcol + srow0) * ldb + scol;
    const u16* Bg1 = BT + (size_t)(bcol + srow0 + 16) * ldb + scol;
    u16* Al0 = As + (wid * 2 + 0) * 512;
    u16* Al1 = As + (wid * 2 + 1) * 512;
    u16* Bl0 = Bs + (wid * 2 + 0) * 512;
    u16* Bl1 = Bs + (wid * 2 + 1) * 512;

    f32x4 acc[4][4] = {};
    for (int k0 = 0; k0 < K; k0 += 32) {
        __syncthreads();
        gload16(Ag0 + k0, Al0);
        gload16(Ag1 + k0, Al1);
        gload16(Bg0 + k0, Bl0);
        gload16(Bg1 + k0, Bl1);
        __syncthreads();
        s16x8 af[4], bf[4];
#pragma unroll
        for (int mi = 0; mi < 4; mi++) af[mi] = *(const s16x8*)(As + (wr + mi * 16 + lr) * 32 + lk);
#pragma unroll
        for (int ni = 0; ni < 4; ni++) bf[ni] = *(const s16x8*)(Bs + (wc + ni * 16 + lr) * 32 + lk);
#pragma unroll
        for (int mi = 0; mi < 4; mi++)
#pragma unroll
            for (int ni = 0; ni < 4; ni++)
                acc[mi][ni] = __builtin_amdgcn_mfma_f32_16x16x32_bf16(af[mi], bf[ni], acc[mi][ni], 0, 0, 0);
    }

    const int drow = ((lane >> 4) << 2);
#pragma unroll
    for (int mi = 0; mi < 4; mi++) {
#pragma unroll
        for (int ni = 0; ni < 4; ni++) {
#pragma unroll
            for (int r = 0; r < 4; r++) {
                int row = brow + wr + mi * 16 + drow + r;
                int col = bcol + wc + ni * 16 + lr;
                float v = acc[mi][ni][r] + bias[col];
                if (OUT_BF16) ((u16*)Cout)[(size_t)row * N + col] = f2bf(v);
                else          ((float*)Cout)[(size_t)row * N + col] = v;
            }
        }
    }
}

// ---------------- RMSNorm + RoPE (Q pre-scaled by 0.125*log2e) ----------------
__global__ __launch_bounds__(64) void k_norm_rope(const float* __restrict__ QKV,
                                                  const float* __restrict__ qn_w, const float* __restrict__ kn_w,
                                                  const float* __restrict__ cosT, const float* __restrict__ sinT,
                                                  u16* __restrict__ Qp, u16* __restrict__ Kp, u16* __restrict__ Vp) {
    int token = blockIdx.x;
    int slot = blockIdx.y;
    int d = threadIdx.x;
    int b = token >> 11, s = token & 2047;
    const float* row = QKV + (size_t)token * NQKV;
    if (slot < 40) {
        bool isq = slot < 32;
        int h = isq ? slot : slot - 32;
        float x = isq ? row[h * HD + d] : row[HID + h * HD + d];
        float ss = x * x;
#pragma unroll
        for (int o = 32; o; o >>= 1) ss += __shfl_xor(ss, o);
        float r = rsqrtf(ss * (1.0f / 64.0f) + 1e-6f);
        float xn = x * r * (isq ? qn_w[d] : kn_w[d]);
        float part = __shfl_xor(xn, 32);
        float sign = (d < 32) ? -1.f : 1.f;
        float o = xn * cosT[s * HD + d] + sign * part * sinT[s * HD + d];
        if (isq) Qp[(((size_t)(b * NH + h) * SEQ + s) * HD) + d] = f2bf(o * QSCALE);
        else     Kp[(((size_t)(b * NKV + h) * SEQ + s) * HD) + d] = f2bf(o);
    } else {
        int h = slot - 40;
        Vp[(((size_t)(b * NKV + h) * SEQ + s) * HD) + d] = f2bf(row[HID + 512 + h * HD + d]);
    }
}

// ---------------- MFMA flash attention v4.1 ----------------
// 4 warps x 32 q-rows, 32x32x16 MFMA, swapped operands (S^T, O^T),
// in-register softmax, P via per-wave LDS [q][key] pad-76 (2-way banks, free),
// setprio around MFMA clusters.
__global__ __launch_bounds__(256) void k_attn_mfma(const u16* __restrict__ Qp, const u16* __restrict__ Kp,
                                                   const u16* __restrict__ VpT, u16* __restrict__ AO) {
    __shared__ u16 K_lds[64 * 64];    // [key][d], 16B slots XOR'd by key&7
    __shared__ u16 VT_lds[64 * 64];   // [d][key], 16B slots XOR'd by d&7
    __shared__ u16 P_lds[4][32][76];  // per-wave, [q][key], pad 76 (bank-free, r5-verified)
    const int bid = blockIdx.x;
    const int qt = 15 - (bid >> 6);   // heavy tiles first
    const int hh = bid & 63;
    const int b = hh >> 5, h = hh & 31, kvh = h >> 2;
    const int t = threadIdx.x, w = t >> 6, lane = t & 63;
    const int q5 = lane & 31, hi = lane >> 5;
    const int qwb = qt * 128 + w * 32;
    const int q_abs = qwb + q5;

    const u16* Qb = Qp + (size_t)(b * NH + h) * SEQ * HD;
    const u16* Kb = Kp + (size_t)(b * NKV + kvh) * SEQ * HD;
    const u16* Vb = VpT + (size_t)(b * NKV + kvh) * HD * SEQ;

    // Q as B-operand: frag[dblk] elem j -> d = dblk*16 + 8*hi + j
    s16x8 qf0 = *(const s16x8*)(Qb + (size_t)q_abs * HD + 0 * 16 + hi * 8);
    s16x8 qf1 = *(const s16x8*)(Qb + (size_t)q_abs * HD + 1 * 16 + hi * 8);
    s16x8 qf2 = *(const s16x8*)(Qb + (size_t)q_abs * HD + 2 * 16 + hi * 8);
    s16x8 qf3 = *(const s16x8*)(Qb + (size_t)q_abs * HD + 3 * 16 + hi * 8);

    f32x16 O0, O1;
#pragma unroll
    for (int r = 0; r < 16; r++) { O0[r] = 0.f; O1[r] = 0.f; }
    float m = -1e30f, l = 0.f;

    const int swz = (q5 & 7) << 4;
    const int nkt = 2 * (qt + 1);
    for (int kt = 0; kt < nkt; kt++) {
        const int k0 = kt * 64;
        __syncthreads();
#pragma unroll
        for (int i = 0; i < 2; i++) {
            int c = (w * 2 + i) * 64 + lane;
            int row = c >> 3, gslot = (c & 7) ^ (row & 7);
            gload16(Kb + (size_t)(k0 + row) * HD + gslot * 8, (char*)K_lds + (size_t)(w * 2 + i) * 1024);
            gload16(Vb + (size_t)row * SEQ + k0 + gslot * 8, (char*)VT_lds + (size_t)(w * 2 + i) * 1024);
        }
        __syncthreads();
        if (k0 > qwb + 31) continue;   // wave-uniform; no barrier below

        // ---- S^T = K Q^T : lane holds q-row q5, keys (r&3)+8*(r>>2)+4*hi (+32 for s1)
        f32x16 s0, s1;
#pragma unroll
        for (int r = 0; r < 16; r++) { s0[r] = 0.f; s1[r] = 0.f; }
        __builtin_amdgcn_s_setprio(1);
#pragma unroll
        for (int dblk = 0; dblk < 4; dblk++) {
            s16x8 kf0 = *(const s16x8*)((const char*)K_lds + q5 * 128 + ((dblk * 32 + hi * 16) ^ swz));
            s16x8 kf1 = *(const s16x8*)((const char*)K_lds + (32 + q5) * 128 + ((dblk * 32 + hi * 16) ^ swz));
            s16x8 qq = (dblk == 0) ? qf0 : (dblk == 1) ? qf1 : (dblk == 2) ? qf2 : qf3;
            s0 = __builtin_amdgcn_mfma_f32_32x32x16_bf16(kf0, qq, s0, 0, 0, 0);
            s1 = __builtin_amdgcn_mfma_f32_32x32x16_bf16(kf1, qq, s1, 0, 0, 0);
        }
        __builtin_amdgcn_s_setprio(0);

        if (k0 + 63 > qwb) {            // diagonal if tile has keys > min q in wave
            const int qrel = q_abs - k0;
#pragma unroll
            for (int r = 0; r < 16; r++) {
                int kr = (r & 3) + 8 * (r >> 2) + 4 * hi;
                if (kr > qrel) s0[r] = -1e30f;
                if (kr + 32 > qrel) s1[r] = -1e30f;
            }
        }

        // ---- online softmax, log2 domain (scale folded into Q) ----
        float mt = -1e30f;
#pragma unroll
        for (int r = 0; r < 16; r++) { mt = fmaxf(mt, s0[r]); mt = fmaxf(mt, s1[r]); }
        mt = fmaxf(mt, __shfl_xor(mt, 32));   // pair-reduce: rescues fully-masked lanes
        if (!__all(mt <= m + 8.0f)) {   // defer-max (T13)
            float mn = fmaxf(m, mt);
            float f = exp2f(m - mn);
            l *= f;
#pragma unroll
            for (int r = 0; r < 16; r++) { O0[r] *= f; O1[r] *= f; }
            m = mn;
        }
        float ps = 0.f;
#pragma unroll
        for (int r = 0; r < 16; r++) {
            float p0 = exp2f(s0[r] - m);
            float p1 = exp2f(s1[r] - m);
            s0[r] = p0; s1[r] = p1;
            ps += p0 + p1;
        }
        ps += __shfl_xor(ps, 32);
        l += ps;

        // ---- P -> per-wave LDS [q][key] (C-layout keys are verified) ----
#pragma unroll
        for (int i = 0; i < 8; i++) {
            int key = 2 * (i & 1) + 8 * (i >> 1) + 4 * hi;   // keys of s[2i],s[2i+1] (adjacent)
            *(unsigned*)&P_lds[w][q5][key]      = cvtpk(s0[2 * i], s0[2 * i + 1]);
            *(unsigned*)&P_lds[w][q5][key + 32] = cvtpk(s1[2 * i], s1[2 * i + 1]);
        }

        // ---- O^T += V^T P^T : both operands loaded with the same assumed map ----
        __builtin_amdgcn_s_setprio(1);
#pragma unroll
        for (int ks = 0; ks < 4; ks++) {
            s16x8 pb  = *(const s16x8*)&P_lds[w][q5][ks * 16 + hi * 8];
            s16x8 vf0 = *(const s16x8*)((const char*)VT_lds + q5 * 128 + ((ks * 32 + hi * 16) ^ swz));
            s16x8 vf1 = *(const s16x8*)((const char*)VT_lds + (32 + q5) * 128 + ((ks * 32 + hi * 16) ^ swz));
            O0 = __builtin_amdgcn_mfma_f32_32x32x16_bf16(vf0, pb, O0, 0, 0, 0);
            O1 = __builtin_amdgcn_mfma_f32_32x32x16_bf16(vf1, pb, O1, 0, 0, 0);
        }
        __builtin_amdgcn_s_setprio(0);
    }

    // ---- epilogue: lane owns q-row q_abs; d = 32*db + 8*g2 + 4*hi + i2 ----
    float inv = 1.0f / l;
    u16* orow = AO + (size_t)(b * SEQ + q_abs) * (NH * HD) + h * HD;
#pragma unroll
    for (int db = 0; db < 2; db++) {
#pragma unroll
        for (int g2 = 0; g2 < 4; g2++) {
            u16x4 wv;
#pragma unroll
            for (int i2 = 0; i2 < 4; i2++) {
                float v = (db == 0 ? O0[g2 * 4 + i2] : O1[g2 * 4 + i2]) * inv;
                wv[i2] = f2bf(v);
            }
            *(u16x4*)(orow + db * 32 + g2 * 8 + hi * 4) = wv;
        }
    }
}

// ---------------- launch ----------------
extern "C" void kernel_launch(void* const* d_in, const int* in_sizes, int n_in,
                              void* d_out, int out_size, void* d_ws, size_t ws_size,
                              hipStream_t stream) {
    const float* hs   = (const float*)d_in[0];
    const float* Wq   = (const float*)d_in[1];
    const float* bq   = (const float*)d_in[2];
    const float* Wk   = (const float*)d_in[3];
    const float* bk   = (const float*)d_in[4];
    const float* Wv   = (const float*)d_in[5];
    const float* bv   = (const float*)d_in[6];
    const float* Wo   = (const float*)d_in[7];
    const float* bo   = (const float*)d_in[8];
    const float* qn_w = (const float*)d_in[9];
    const float* kn_w = (const float*)d_in[10];
    const float* cosT = (const float*)d_in[11];
    const float* sinT = (const float*)d_in[12];

    char* ws = (char*)d_ws;
    size_t off = 0;
    auto alloc = [&](size_t bytes) { char* p = ws + off; off = (off + bytes + 255) & ~(size_t)255; return p; };
    u16*   Xb    = (u16*)  alloc((size_t)TOK * HID * 2);
    u16*   WTqkv = (u16*)  alloc((size_t)NQKV * HID * 2);
    u16*   WoT   = (u16*)  alloc((size_t)HID * HID * 2);
    float* bqkv  = (float*)alloc((size_t)NQKV * 4);
    float* QKV   = (float*)alloc((size_t)TOK * NQKV * 4);
    u16*   Qp    = (u16*)  alloc((size_t)BATCH * NH * SEQ * HD * 2);
    u16*   Kp    = (u16*)  alloc((size_t)BATCH * NKV * SEQ * HD * 2);
    u16*   Vp    = (u16*)  alloc((size_t)BATCH * NKV * SEQ * HD * 2);
    u16*   VpT   = (u16*)  alloc((size_t)BATCH * NKV * SEQ * HD * 2);
    u16*   AO    = (u16*)  alloc((size_t)TOK * HID * 2);
    (void)ws_size;

    k_f32_to_bf16<<<(TOK * HID / 4 + 255) / 256, 256, 0, stream>>>(hs, Xb, TOK * HID / 4);
    dim3 tb(32, 8);
    k_transpose_bf16<<<dim3(HID / 32, HID / 32), tb, 0, stream>>>(Wq, WTqkv, HID, HID);
    k_transpose_bf16<<<dim3(512 / 32, HID / 32), tb, 0, stream>>>(Wk, WTqkv + (size_t)HID * HID, HID, 512);
    k_transpose_bf16<<<dim3(512 / 32, HID / 32), tb, 0, stream>>>(Wv, WTqkv + (size_t)(HID + 512) * HID, HID, 512);
    k_transpose_bf16<<<dim3(HID / 32, HID / 32), tb, 0, stream>>>(Wo, WoT, HID, HID);
    k_concat_bias<<<(NQKV + 255) / 256, 256, 0, stream>>>(bq, bk, bv, bqkv);
    // QKV GEMM -> f32   (grid 24x32 = 768 blocks, %8==0 for swizzle)
    k_gemm_bt<0><<<dim3(NQKV / 128, TOK / 128), 256, 0, stream>>>(Xb, WTqkv, bqkv, QKV, TOK, NQKV, HID, HID, HID);
    // norm + rope
    k_norm_rope<<<dim3(TOK, 48), 64, 0, stream>>>(QKV, qn_w, kn_w, cosT, sinT, Qp, Kp, Vp);
    // V transpose per head
    k_transpose_v<<<dim3(HD / 32, SEQ / 32, BATCH * NKV), tb, 0, stream>>>(Vp, VpT);
    // MFMA flash attention v4.1
    k_attn_mfma<<<BATCH * NH * (SEQ / 128), 256, 0, stream>>>(Qp, Kp, VpT, AO);
    // output projection -> f32 d_out   (grid 16x32 = 512 blocks)
    k_gemm_bt<0><<<dim3(HID / 128, TOK / 128), 256, 0, stream>>>(AO, WoT, bo, d_out, TOK, HID, HID, HID, HID);
}